// Round 1
// baseline (545.361 us; speedup 1.0000x reference)
//
#include <hip/hip_runtime.h>

// Problem dims (LRNetLinear): out = B x O, x = B x I, weights O x I
#define I_DIM 4096
#define O_DIM 4096
#define B_DIM 4096

typedef _Float16 f16;
typedef __attribute__((ext_vector_type(8))) _Float16 f16x8;
typedef __attribute__((ext_vector_type(4))) float f32x4;

struct f16pair { f16 m, v; };

// ---------------------------------------------------------------------------
// Weight transform: 3-way softmax stats -> (w_mean, w_var) in fp16
// ---------------------------------------------------------------------------
__device__ inline f16pair lr_wmv(float tn, float tp, float s) {
    float m = fmaxf(fmaxf(tn, tp), 0.0f);
    float en = __expf(tn - m);
    float ez = __expf(-m);
    float ep = __expf(tp - m);
    float inv = __builtin_amdgcn_rcpf(en + ez + ep);
    float pn = en * inv, pp = ep * inv;
    float d = pp - pn;
    f16pair r;
    r.m = (f16)(d * s);
    r.v = (f16)((pp + pn - d * d) * (s * s));
    return r;
}

// ---------------------------------------------------------------------------
// Fused prep (8 elems/thread both paths) — unchanged this round.
// ---------------------------------------------------------------------------
__global__ void prep_all(const float4* __restrict__ x, f16x8* __restrict__ xb8,
                         const float4* __restrict__ tn4, const float4* __restrict__ tp4,
                         const float4* __restrict__ sc4,
                         f16x8* __restrict__ wm8, f16x8* __restrict__ wv8,
                         int nbx) {
    const int bid = blockIdx.x;
    if (bid < nbx) {
        size_t i = (size_t)bid * blockDim.x + threadIdx.x;
        float4 a = x[2 * i];
        float4 b = x[2 * i + 1];
        f16x8 o;
        o[0] = (f16)a.x; o[1] = (f16)a.y; o[2] = (f16)a.z; o[3] = (f16)a.w;
        o[4] = (f16)b.x; o[5] = (f16)b.y; o[6] = (f16)b.z; o[7] = (f16)b.w;
        xb8[i] = o;
    } else {
        size_t i = (size_t)(bid - nbx) * blockDim.x + threadIdx.x;
        float4 a0 = tn4[2 * i], a1 = tn4[2 * i + 1];
        float4 b0 = tp4[2 * i], b1 = tp4[2 * i + 1];
        float4 s0 = sc4[2 * i], s1 = sc4[2 * i + 1];
        f16x8 om, ov;
        f16pair p;
        p = lr_wmv(a0.x, b0.x, s0.x); om[0] = p.m; ov[0] = p.v;
        p = lr_wmv(a0.y, b0.y, s0.y); om[1] = p.m; ov[1] = p.v;
        p = lr_wmv(a0.z, b0.z, s0.z); om[2] = p.m; ov[2] = p.v;
        p = lr_wmv(a0.w, b0.w, s0.w); om[3] = p.m; ov[3] = p.v;
        p = lr_wmv(a1.x, b1.x, s1.x); om[4] = p.m; ov[4] = p.v;
        p = lr_wmv(a1.y, b1.y, s1.y); om[5] = p.m; ov[5] = p.v;
        p = lr_wmv(a1.z, b1.z, s1.z); om[6] = p.m; ov[6] = p.v;
        p = lr_wmv(a1.w, b1.w, s1.w); om[7] = p.m; ov[7] = p.v;
        wm8[i] = om;
        wv8[i] = ov;
    }
}

// ---------------------------------------------------------------------------
// Fused dual GEMM, 8-phase counted-vmcnt pipeline (T2+T3+T4+T5):
//   BM=256 x BN=128, BK=64, 512 threads = 8 waves (4M x 2N), each wave a
//   64x64 DUAL accumulator (A^2 formed in-register).
//   LDS 128 KB = 2 K-tile buffers x {X 32K | Wm 16K | Wv 16K}, kh-sliced
//   into 16KB units. Layout: 64B rows (32 f16), granule swizzle
//   g ^= (row>>1)&3  (2 lanes/bank-position per 16-lane group => conflict-free),
//   realized by pre-swizzling the GLOBAL source (gl_lds dest stays linear).
//   Schedule per 2-K-tile iteration: 8 phases, each = {ds_read frags |
//   issue 1 staging unit (2 gl_lds)} -> s_barrier -> lgkmcnt(0) ->
//   setprio(1) 16 MFMA setprio(0) -> [odd phases: vmcnt(6)] -> s_barrier.
//   vmcnt never drains to 0 in the main loop; 6 loads (3 units) stay in
//   flight across every barrier. Hand-verified: every LDS region is
//   overwritten >=1 phase after its last read, and every ds_read target was
//   forced complete by a vmcnt >=3 phases after its issue + barrier-published.
// ---------------------------------------------------------------------------
#define BM 256
#define BN 128
#define BK 64

__device__ inline void gl_lds16(const f16* g, f16* l) {
    __builtin_amdgcn_global_load_lds(
        (const __attribute__((address_space(1))) unsigned int*)g,
        (__attribute__((address_space(3))) unsigned int*)l,
        16, 0, 0);
}

#define VM8 asm volatile("s_waitcnt vmcnt(8)")
#define VM6 asm volatile("s_waitcnt vmcnt(6)")
#define VM4 asm volatile("s_waitcnt vmcnt(4)")
#define VM0 asm volatile("s_waitcnt vmcnt(0)")
#define VMNONE (void)0

__global__ __launch_bounds__(512, 2)
void fused_dual_gemm(const f16* __restrict__ Xb,
                     const f16* __restrict__ Wm, const f16* __restrict__ Wv,
                     const float* __restrict__ eps, float* __restrict__ out) {
    __shared__ f16 smem[65536];                // 128 KB: [parity 32768][...]
    // elem offsets: X(p,kh) = p*32768 + kh*8192            (256 rows x 32)
    //               Wm(p,kh) = 16384 + p*32768 + kh*8192   (128 rows x 32)
    //               Wv(p,kh) = Wm + 4096

    const int tid  = threadIdx.x;
    const int lane = tid & 63;
    const int wave = tid >> 6;

    const int bm = blockIdx.y * BM;
    const int bn = blockIdx.x * BN;

    // ---- staging source (per-lane pre-swizzled granule): chunk = 16 rows x 64B.
    // lane -> row = lane>>2, stored slot = lane&3, logical granule = slot ^ ((row>>1)&3)
    const int srow = lane >> 2;
    const int scol = (((lane & 3) ^ ((lane >> 3) & 3)) << 3);   // elems
    const f16* gX = Xb + (size_t)(bm + 32 * wave + srow) * I_DIM + scol;  // 2 chunks: rows 32w..32w+31
    const f16* gM = Wm + (size_t)(bn + 16 * wave + srow) * I_DIM + scol;  // 1 chunk:  rows 16w..16w+15
    const f16* gV = Wv + (size_t)(bn + 16 * wave + srow) * I_DIM + scol;
    f16* ldsX = smem + wave * 1024;            // + p*32768 + kh*8192 (+512 for chunk 1)
    f16* ldsW = smem + 16384 + wave * 512;     // + p*32768 + kh*8192 (+4096 for Wv)

    // ---- fragment geometry (16x16x32: row = lane&15, granule = lane>>4)
    const int fr  = lane & 15;
    const int sg8 = (((lane >> 4) ^ ((fr >> 1) & 3)) << 3);     // swizzled granule, elems
    const int m0 = (wave >> 1) << 6;           // 4 M-waves: 0,64,128,192
    const int n0 = (wave & 1) << 6;            // 2 N-waves: 0,64

    f32x4 accM[4][4];
    f32x4 accV[4][4];
    const f32x4 z = {0.0f, 0.0f, 0.0f, 0.0f};
#pragma unroll
    for (int mi = 0; mi < 4; ++mi)
#pragma unroll
        for (int ni = 0; ni < 4; ++ni) { accM[mi][ni] = z; accV[mi][ni] = z; }

    f16x8 a[4], a2[4];

#define STAGE_X(kelem, reg) do {                                               \
        gl_lds16(gX + (kelem),              ldsX + (reg));                     \
        gl_lds16(gX + (kelem) + 16 * I_DIM, ldsX + (reg) + 512);               \
    } while (0)
#define STAGE_W(kelem, reg) do {                                               \
        gl_lds16(gM + (kelem), ldsW + (reg));                                  \
        gl_lds16(gV + (kelem), ldsW + (reg) + 4096);                           \
    } while (0)

#define PHASE(RX, RW, NH, STG, VM) do {                                        \
        if ((NH) == 0) {                                                       \
            _Pragma("unroll")                                                  \
            for (int mi = 0; mi < 4; ++mi) {                                   \
                a[mi]  = *(const f16x8*)(smem + (RX) + (m0 + mi * 16 + fr) * 32 + sg8); \
                a2[mi] = a[mi] * a[mi];                                        \
            }                                                                  \
        }                                                                      \
        const f16x8 b0m = *(const f16x8*)(smem + (RW)        + (n0 + ((NH) * 2 + 0) * 16 + fr) * 32 + sg8); \
        const f16x8 b0v = *(const f16x8*)(smem + (RW) + 4096 + (n0 + ((NH) * 2 + 0) * 16 + fr) * 32 + sg8); \
        const f16x8 b1m = *(const f16x8*)(smem + (RW)        + (n0 + ((NH) * 2 + 1) * 16 + fr) * 32 + sg8); \
        const f16x8 b1v = *(const f16x8*)(smem + (RW) + 4096 + (n0 + ((NH) * 2 + 1) * 16 + fr) * 32 + sg8); \
        STG;                                                                   \
        __builtin_amdgcn_s_barrier();                                          \
        asm volatile("s_waitcnt lgkmcnt(0)");                                  \
        __builtin_amdgcn_sched_barrier(0);                                     \
        __builtin_amdgcn_s_setprio(1);                                         \
        _Pragma("unroll")                                                      \
        for (int mi = 0; mi < 4; ++mi) {                                       \
            accM[mi][(NH) * 2 + 0] = __builtin_amdgcn_mfma_f32_16x16x32_f16(a[mi],  b0m, accM[mi][(NH) * 2 + 0], 0, 0, 0); \
            accV[mi][(NH) * 2 + 0] = __builtin_amdgcn_mfma_f32_16x16x32_f16(a2[mi], b0v, accV[mi][(NH) * 2 + 0], 0, 0, 0); \
            accM[mi][(NH) * 2 + 1] = __builtin_amdgcn_mfma_f32_16x16x32_f16(a[mi],  b1m, accM[mi][(NH) * 2 + 1], 0, 0, 0); \
            accV[mi][(NH) * 2 + 1] = __builtin_amdgcn_mfma_f32_16x16x32_f16(a2[mi], b1v, accV[mi][(NH) * 2 + 1], 0, 0, 0); \
        }                                                                      \
        __builtin_amdgcn_s_setprio(0);                                         \
        VM;                                                                    \
        __builtin_amdgcn_s_barrier();                                          \
    } while (0)

    // ---- prologue: stage {X,W}(t0)k0, {X,W}(t0)k1, {X,W}(t1)k0 = 12 loads;
    // force the 4 oldest (tile0 kh0) before phase 0's ds_reads.
    STAGE_X(0, 0);      STAGE_W(0, 0);
    STAGE_X(32, 8192);  STAGE_W(32, 8192);
    STAGE_X(64, 32768); STAGE_W(64, 32768);
    VM8;
    __builtin_amdgcn_s_barrier();

    // ---- main loop: 31 iterations x 2 K-tiles (tiles 0..61), prefetching 2 ahead
#pragma unroll 1
    for (int i = 0; i < 31; ++i) {
        const int kb = i * 128;
        PHASE(0,     16384, 0, STAGE_X(kb +  96, 40960), VMNONE);  // t0 kh0 | issue X(t1)k1
        PHASE(0,     16384, 1, STAGE_W(kb +  96, 40960), VM6);     //        | issue W(t1)k1
        PHASE(8192,  24576, 0, STAGE_X(kb + 128,     0), VMNONE);  // t0 kh1 | issue X(t0+2)k0
        PHASE(8192,  24576, 1, STAGE_W(kb + 128,     0), VM6);     //        | issue W(t0+2)k0
        PHASE(32768, 49152, 0, STAGE_X(kb + 160,  8192), VMNONE);  // t1 kh0 | issue X(t0+2)k1
        PHASE(32768, 49152, 1, STAGE_W(kb + 160,  8192), VM6);     //        | issue W(t0+2)k1
        PHASE(40960, 57344, 0, STAGE_X(kb + 192, 32768), VMNONE);  // t1 kh1 | issue X(t1+2)k0
        PHASE(40960, 57344, 1, STAGE_W(kb + 192, 32768), VM6);     //        | issue W(t1+2)k0
    }

    // ---- tail: tiles 62,63 (only X/W(63)k1 still to issue), drain 6->4->0
    PHASE(0,     16384, 0, STAGE_X(4064, 40960), VMNONE);
    PHASE(0,     16384, 1, STAGE_W(4064, 40960), VM6);
    PHASE(8192,  24576, 0, VMNONE, VMNONE);
    PHASE(8192,  24576, 1, VMNONE, VM4);
    PHASE(32768, 49152, 0, VMNONE, VMNONE);
    PHASE(32768, 49152, 1, VMNONE, VM0);
    PHASE(40960, 57344, 0, VMNONE, VMNONE);
    PHASE(40960, 57344, 1, VMNONE, VMNONE);

    // ---- epilogue (register-resident): C/D layout col = lane&15, row = (lane>>4)*4 + r
    const int oc  = lane & 15;
    const int orb = (lane >> 4) << 2;
#pragma unroll
    for (int mi = 0; mi < 4; ++mi) {
#pragma unroll
        for (int ni = 0; ni < 4; ++ni) {
            const int gn = bn + n0 + ni * 16 + oc;
            const int gm = bm + m0 + mi * 16 + orb;
#pragma unroll
            for (int r = 0; r < 4; ++r) {
                const size_t off = (size_t)(gm + r) * O_DIM + gn;
                const float mu = accM[mi][ni][r];
                const float vv = accV[mi][ni][r];
                out[off] = fmaf(sqrtf(fmaxf(vv, 1e-8f)), eps[off], mu);
            }
        }
    }
#undef PHASE
#undef STAGE_X
#undef STAGE_W
}

// ---------------------------------------------------------------------------
extern "C" void kernel_launch(void* const* d_in, const int* in_sizes, int n_in,
                              void* d_out, int out_size, void* d_ws, size_t ws_size,
                              hipStream_t stream) {
    const float* x   = (const float*)d_in[0];
    const float* tn  = (const float*)d_in[1];
    const float* tp  = (const float*)d_in[2];
    const float* sc  = (const float*)d_in[3];
    const float* eps = (const float*)d_in[4];
    float* out = (float*)d_out;

    const size_t NE = (size_t)O_DIM * I_DIM;   // 16.7M
    f16* xb = (f16*)d_ws;                      // 32 MB
    f16* wm = xb + NE;                         // 32 MB
    f16* wv = wm + NE;                         // 32 MB

    const int nbx = (int)(NE / 8 / 256);       // 8192 (x path)
    const int nbw = (int)(NE / 8 / 256);       // 8192 (weight path)
    prep_all<<<nbx + nbw, 256, 0, stream>>>(
        (const float4*)x, (f16x8*)xb,
        (const float4*)tn, (const float4*)tp, (const float4*)sc,
        (f16x8*)wm, (f16x8*)wv, nbx);

    dim3 grid(O_DIM / BN, B_DIM / BM);   // (32, 16)
    fused_dual_gemm<<<grid, 512, 0, stream>>>(
        (const f16*)xb, (const f16*)wm, (const f16*)wv, eps, out);
}

// Round 2
// 545.048 us; speedup vs baseline: 1.0006x; 1.0006x over previous
//
#include <hip/hip_runtime.h>

// Problem dims (LRNetLinear): out = B x O, x = B x I, weights O x I
#define I_DIM 4096
#define O_DIM 4096
#define B_DIM 4096

typedef _Float16 f16;
typedef __attribute__((ext_vector_type(8))) _Float16 f16x8;
typedef __attribute__((ext_vector_type(4))) float f32x4;

struct f16pair { f16 m, v; };

// ---------------------------------------------------------------------------
// Weight transform: 3-way softmax stats -> (w_mean, w_var) in fp16
// ---------------------------------------------------------------------------
__device__ inline f16pair lr_wmv(float tn, float tp, float s) {
    float m = fmaxf(fmaxf(tn, tp), 0.0f);
    float en = __expf(tn - m);
    float ez = __expf(-m);
    float ep = __expf(tp - m);
    float inv = __builtin_amdgcn_rcpf(en + ez + ep);
    float pn = en * inv, pp = ep * inv;
    float d = pp - pn;
    f16pair r;
    r.m = (f16)(d * s);
    r.v = (f16)((pp + pn - d * d) * (s * s));
    return r;
}

// ---------------------------------------------------------------------------
// Fused prep (8 elems/thread both paths) — unchanged this round.
// ---------------------------------------------------------------------------
__global__ void prep_all(const float4* __restrict__ x, f16x8* __restrict__ xb8,
                         const float4* __restrict__ tn4, const float4* __restrict__ tp4,
                         const float4* __restrict__ sc4,
                         f16x8* __restrict__ wm8, f16x8* __restrict__ wv8,
                         int nbx) {
    const int bid = blockIdx.x;
    if (bid < nbx) {
        size_t i = (size_t)bid * blockDim.x + threadIdx.x;
        float4 a = x[2 * i];
        float4 b = x[2 * i + 1];
        f16x8 o;
        o[0] = (f16)a.x; o[1] = (f16)a.y; o[2] = (f16)a.z; o[3] = (f16)a.w;
        o[4] = (f16)b.x; o[5] = (f16)b.y; o[6] = (f16)b.z; o[7] = (f16)b.w;
        xb8[i] = o;
    } else {
        size_t i = (size_t)(bid - nbx) * blockDim.x + threadIdx.x;
        float4 a0 = tn4[2 * i], a1 = tn4[2 * i + 1];
        float4 b0 = tp4[2 * i], b1 = tp4[2 * i + 1];
        float4 s0 = sc4[2 * i], s1 = sc4[2 * i + 1];
        f16x8 om, ov;
        f16pair p;
        p = lr_wmv(a0.x, b0.x, s0.x); om[0] = p.m; ov[0] = p.v;
        p = lr_wmv(a0.y, b0.y, s0.y); om[1] = p.m; ov[1] = p.v;
        p = lr_wmv(a0.z, b0.z, s0.z); om[2] = p.m; ov[2] = p.v;
        p = lr_wmv(a0.w, b0.w, s0.w); om[3] = p.m; ov[3] = p.v;
        p = lr_wmv(a1.x, b1.x, s1.x); om[4] = p.m; ov[4] = p.v;
        p = lr_wmv(a1.y, b1.y, s1.y); om[5] = p.m; ov[5] = p.v;
        p = lr_wmv(a1.z, b1.z, s1.z); om[6] = p.m; ov[6] = p.v;
        p = lr_wmv(a1.w, b1.w, s1.w); om[7] = p.m; ov[7] = p.v;
        wm8[i] = om;
        wv8[i] = ov;
    }
}

// ---------------------------------------------------------------------------
// Fused dual GEMM, 8-phase counted-vmcnt pipeline (T2+T3+T4+T5):
//   BM=256 x BN=128, BK=64, 512 threads = 8 waves (4M x 2N), each wave a
//   64x64 DUAL accumulator (A^2 formed in-register).
//   LDS 128 KB = 2 K-tile buffers x {X 32K | Wm 16K | Wv 16K}, kh-sliced
//   into 16KB units; 64B rows, XOR granule swizzle (conflict-free, measured 0).
//   ROUND-2 CHANGE: removed the blunt `lgkmcnt(0)+sched_barrier(0)` drain
//   before the MFMA cluster. Our ds_reads are compiler-visible C++ loads, so
//   the compiler emits fine-grained per-dependency lgkmcnt(N) — first MFMAs
//   issue while later reads still drain, overlapping the ~1130cy LDS-port
//   burst with the 1242cy MFMA block instead of serializing them.
//   All reads are consumed within their phase (deps force completion before
//   the end barrier), staging overwrite of any region is >=2 barriers after
//   its reads, vmcnt(6) publication schedule unchanged -> no new hazards.
// ---------------------------------------------------------------------------
#define BM 256
#define BN 128
#define BK 64

__device__ inline void gl_lds16(const f16* g, f16* l) {
    __builtin_amdgcn_global_load_lds(
        (const __attribute__((address_space(1))) unsigned int*)g,
        (__attribute__((address_space(3))) unsigned int*)l,
        16, 0, 0);
}

#define VM8 asm volatile("s_waitcnt vmcnt(8)")
#define VM6 asm volatile("s_waitcnt vmcnt(6)")
#define VM4 asm volatile("s_waitcnt vmcnt(4)")
#define VM0 asm volatile("s_waitcnt vmcnt(0)")
#define VMNONE (void)0

__global__ __launch_bounds__(512, 2)
void fused_dual_gemm(const f16* __restrict__ Xb,
                     const f16* __restrict__ Wm, const f16* __restrict__ Wv,
                     const float* __restrict__ eps, float* __restrict__ out) {
    __shared__ f16 smem[65536];                // 128 KB: [parity 32768][...]
    // elem offsets: X(p,kh) = p*32768 + kh*8192            (256 rows x 32)
    //               Wm(p,kh) = 16384 + p*32768 + kh*8192   (128 rows x 32)
    //               Wv(p,kh) = Wm + 4096

    const int tid  = threadIdx.x;
    const int lane = tid & 63;
    const int wave = tid >> 6;

    const int bm = blockIdx.y * BM;
    const int bn = blockIdx.x * BN;

    // ---- staging source (per-lane pre-swizzled granule): chunk = 16 rows x 64B.
    // lane -> row = lane>>2, stored slot = lane&3, logical granule = slot ^ ((row>>1)&3)
    const int srow = lane >> 2;
    const int scol = (((lane & 3) ^ ((lane >> 3) & 3)) << 3);   // elems
    const f16* gX = Xb + (size_t)(bm + 32 * wave + srow) * I_DIM + scol;  // 2 chunks: rows 32w..32w+31
    const f16* gM = Wm + (size_t)(bn + 16 * wave + srow) * I_DIM + scol;  // 1 chunk:  rows 16w..16w+15
    const f16* gV = Wv + (size_t)(bn + 16 * wave + srow) * I_DIM + scol;
    f16* ldsX = smem + wave * 1024;            // + p*32768 + kh*8192 (+512 for chunk 1)
    f16* ldsW = smem + 16384 + wave * 512;     // + p*32768 + kh*8192 (+4096 for Wv)

    // ---- fragment geometry (16x16x32: row = lane&15, granule = lane>>4)
    const int fr  = lane & 15;
    const int sg8 = (((lane >> 4) ^ ((fr >> 1) & 3)) << 3);     // swizzled granule, elems
    const int m0 = (wave >> 1) << 6;           // 4 M-waves: 0,64,128,192
    const int n0 = (wave & 1) << 6;            // 2 N-waves: 0,64

    f32x4 accM[4][4];
    f32x4 accV[4][4];
    const f32x4 z = {0.0f, 0.0f, 0.0f, 0.0f};
#pragma unroll
    for (int mi = 0; mi < 4; ++mi)
#pragma unroll
        for (int ni = 0; ni < 4; ++ni) { accM[mi][ni] = z; accV[mi][ni] = z; }

    f16x8 a[4], a2[4];

#define STAGE_X(kelem, reg) do {                                               \
        gl_lds16(gX + (kelem),              ldsX + (reg));                     \
        gl_lds16(gX + (kelem) + 16 * I_DIM, ldsX + (reg) + 512);               \
    } while (0)
#define STAGE_W(kelem, reg) do {                                               \
        gl_lds16(gM + (kelem), ldsW + (reg));                                  \
        gl_lds16(gV + (kelem), ldsW + (reg) + 4096);                           \
    } while (0)

#define PHASE(RX, RW, NH, STG, VM) do {                                        \
        if ((NH) == 0) {                                                       \
            _Pragma("unroll")                                                  \
            for (int mi = 0; mi < 4; ++mi) {                                   \
                a[mi]  = *(const f16x8*)(smem + (RX) + (m0 + mi * 16 + fr) * 32 + sg8); \
                a2[mi] = a[mi] * a[mi];                                        \
            }                                                                  \
        }                                                                      \
        const f16x8 b0m = *(const f16x8*)(smem + (RW)        + (n0 + ((NH) * 2 + 0) * 16 + fr) * 32 + sg8); \
        const f16x8 b0v = *(const f16x8*)(smem + (RW) + 4096 + (n0 + ((NH) * 2 + 0) * 16 + fr) * 32 + sg8); \
        const f16x8 b1m = *(const f16x8*)(smem + (RW)        + (n0 + ((NH) * 2 + 1) * 16 + fr) * 32 + sg8); \
        const f16x8 b1v = *(const f16x8*)(smem + (RW) + 4096 + (n0 + ((NH) * 2 + 1) * 16 + fr) * 32 + sg8); \
        STG;                                                                   \
        __builtin_amdgcn_s_barrier();                                          \
        __builtin_amdgcn_s_setprio(1);                                         \
        _Pragma("unroll")                                                      \
        for (int mi = 0; mi < 4; ++mi) {                                       \
            accM[mi][(NH) * 2 + 0] = __builtin_amdgcn_mfma_f32_16x16x32_f16(a[mi],  b0m, accM[mi][(NH) * 2 + 0], 0, 0, 0); \
            accV[mi][(NH) * 2 + 0] = __builtin_amdgcn_mfma_f32_16x16x32_f16(a2[mi], b0v, accV[mi][(NH) * 2 + 0], 0, 0, 0); \
            accM[mi][(NH) * 2 + 1] = __builtin_amdgcn_mfma_f32_16x16x32_f16(a[mi],  b1m, accM[mi][(NH) * 2 + 1], 0, 0, 0); \
            accV[mi][(NH) * 2 + 1] = __builtin_amdgcn_mfma_f32_16x16x32_f16(a2[mi], b1v, accV[mi][(NH) * 2 + 1], 0, 0, 0); \
        }                                                                      \
        __builtin_amdgcn_s_setprio(0);                                         \
        VM;                                                                    \
        __builtin_amdgcn_s_barrier();                                          \
    } while (0)

    // ---- prologue: stage {X,W}(t0)k0, {X,W}(t0)k1, {X,W}(t1)k0 = 12 loads;
    // force the 4 oldest (tile0 kh0) before phase 0's ds_reads.
    STAGE_X(0, 0);      STAGE_W(0, 0);
    STAGE_X(32, 8192);  STAGE_W(32, 8192);
    STAGE_X(64, 32768); STAGE_W(64, 32768);
    VM8;
    __builtin_amdgcn_s_barrier();

    // ---- main loop: 31 iterations x 2 K-tiles (tiles 0..61), prefetching 2 ahead
#pragma unroll 1
    for (int i = 0; i < 31; ++i) {
        const int kb = i * 128;
        PHASE(0,     16384, 0, STAGE_X(kb +  96, 40960), VMNONE);  // t0 kh0 | issue X(t1)k1
        PHASE(0,     16384, 1, STAGE_W(kb +  96, 40960), VM6);     //        | issue W(t1)k1
        PHASE(8192,  24576, 0, STAGE_X(kb + 128,     0), VMNONE);  // t0 kh1 | issue X(t0+2)k0
        PHASE(8192,  24576, 1, STAGE_W(kb + 128,     0), VM6);     //        | issue W(t0+2)k0
        PHASE(32768, 49152, 0, STAGE_X(kb + 160,  8192), VMNONE);  // t1 kh0 | issue X(t0+2)k1
        PHASE(32768, 49152, 1, STAGE_W(kb + 160,  8192), VM6);     //        | issue W(t0+2)k1
        PHASE(40960, 57344, 0, STAGE_X(kb + 192, 32768), VMNONE);  // t1 kh1 | issue X(t1+2)k0
        PHASE(40960, 57344, 1, STAGE_W(kb + 192, 32768), VM6);     //        | issue W(t1+2)k0
    }

    // ---- tail: tiles 62,63 (only X/W(63)k1 still to issue), drain 6->4->0
    PHASE(0,     16384, 0, STAGE_X(4064, 40960), VMNONE);
    PHASE(0,     16384, 1, STAGE_W(4064, 40960), VM6);
    PHASE(8192,  24576, 0, VMNONE, VMNONE);
    PHASE(8192,  24576, 1, VMNONE, VM4);
    PHASE(32768, 49152, 0, VMNONE, VMNONE);
    PHASE(32768, 49152, 1, VMNONE, VM0);
    PHASE(40960, 57344, 0, VMNONE, VMNONE);
    PHASE(40960, 57344, 1, VMNONE, VMNONE);

    // ---- epilogue (register-resident): C/D layout col = lane&15, row = (lane>>4)*4 + r
    const int oc  = lane & 15;
    const int orb = (lane >> 4) << 2;
#pragma unroll
    for (int mi = 0; mi < 4; ++mi) {
#pragma unroll
        for (int ni = 0; ni < 4; ++ni) {
            const int gn = bn + n0 + ni * 16 + oc;
            const int gm = bm + m0 + mi * 16 + orb;
#pragma unroll
            for (int r = 0; r < 4; ++r) {
                const size_t off = (size_t)(gm + r) * O_DIM + gn;
                const float mu = accM[mi][ni][r];
                const float vv = accV[mi][ni][r];
                out[off] = fmaf(sqrtf(fmaxf(vv, 1e-8f)), eps[off], mu);
            }
        }
    }
#undef PHASE
#undef STAGE_X
#undef STAGE_W
}

// ---------------------------------------------------------------------------
extern "C" void kernel_launch(void* const* d_in, const int* in_sizes, int n_in,
                              void* d_out, int out_size, void* d_ws, size_t ws_size,
                              hipStream_t stream) {
    const float* x   = (const float*)d_in[0];
    const float* tn  = (const float*)d_in[1];
    const float* tp  = (const float*)d_in[2];
    const float* sc  = (const float*)d_in[3];
    const float* eps = (const float*)d_in[4];
    float* out = (float*)d_out;

    const size_t NE = (size_t)O_DIM * I_DIM;   // 16.7M
    f16* xb = (f16*)d_ws;                      // 32 MB
    f16* wm = xb + NE;                         // 32 MB
    f16* wv = wm + NE;                         // 32 MB

    const int nbx = (int)(NE / 8 / 256);       // 8192 (x path)
    const int nbw = (int)(NE / 8 / 256);       // 8192 (weight path)
    prep_all<<<nbx + nbw, 256, 0, stream>>>(
        (const float4*)x, (f16x8*)xb,
        (const float4*)tn, (const float4*)tp, (const float4*)sc,
        (f16x8*)wm, (f16x8*)wv, nbx);

    dim3 grid(O_DIM / BN, B_DIM / BM);   // (32, 16)
    fused_dual_gemm<<<grid, 512, 0, stream>>>(
        (const f16*)xb, (const f16*)wm, (const f16*)wv, eps, out);
}

// Round 3
// 535.507 us; speedup vs baseline: 1.0184x; 1.0178x over previous
//
#include <hip/hip_runtime.h>

// Problem dims (LRNetLinear): out = B x O, x = B x I, weights O x I
#define I_DIM 4096
#define O_DIM 4096
#define B_DIM 4096

typedef _Float16 f16;
typedef __attribute__((ext_vector_type(8))) _Float16 f16x8;
typedef __attribute__((ext_vector_type(4))) float f32x4;

struct f16pair { f16 m, v; };

// ---------------------------------------------------------------------------
// Weight transform: 3-way softmax stats -> (w_mean, w_var) in fp16
// ---------------------------------------------------------------------------
__device__ inline f16pair lr_wmv(float tn, float tp, float s) {
    float m = fmaxf(fmaxf(tn, tp), 0.0f);
    float en = __expf(tn - m);
    float ez = __expf(-m);
    float ep = __expf(tp - m);
    float inv = __builtin_amdgcn_rcpf(en + ez + ep);
    float pn = en * inv, pp = ep * inv;
    float d = pp - pn;
    f16pair r;
    r.m = (f16)(d * s);
    r.v = (f16)((pp + pn - d * d) * (s * s));
    return r;
}

// ---------------------------------------------------------------------------
// Fused prep (8 elems/thread both paths) — unchanged this round.
// ---------------------------------------------------------------------------
__global__ void prep_all(const float4* __restrict__ x, f16x8* __restrict__ xb8,
                         const float4* __restrict__ tn4, const float4* __restrict__ tp4,
                         const float4* __restrict__ sc4,
                         f16x8* __restrict__ wm8, f16x8* __restrict__ wv8,
                         int nbx) {
    const int bid = blockIdx.x;
    if (bid < nbx) {
        size_t i = (size_t)bid * blockDim.x + threadIdx.x;
        float4 a = x[2 * i];
        float4 b = x[2 * i + 1];
        f16x8 o;
        o[0] = (f16)a.x; o[1] = (f16)a.y; o[2] = (f16)a.z; o[3] = (f16)a.w;
        o[4] = (f16)b.x; o[5] = (f16)b.y; o[6] = (f16)b.z; o[7] = (f16)b.w;
        xb8[i] = o;
    } else {
        size_t i = (size_t)(bid - nbx) * blockDim.x + threadIdx.x;
        float4 a0 = tn4[2 * i], a1 = tn4[2 * i + 1];
        float4 b0 = tp4[2 * i], b1 = tp4[2 * i + 1];
        float4 s0 = sc4[2 * i], s1 = sc4[2 * i + 1];
        f16x8 om, ov;
        f16pair p;
        p = lr_wmv(a0.x, b0.x, s0.x); om[0] = p.m; ov[0] = p.v;
        p = lr_wmv(a0.y, b0.y, s0.y); om[1] = p.m; ov[1] = p.v;
        p = lr_wmv(a0.z, b0.z, s0.z); om[2] = p.m; ov[2] = p.v;
        p = lr_wmv(a0.w, b0.w, s0.w); om[3] = p.m; ov[3] = p.v;
        p = lr_wmv(a1.x, b1.x, s1.x); om[4] = p.m; ov[4] = p.v;
        p = lr_wmv(a1.y, b1.y, s1.y); om[5] = p.m; ov[5] = p.v;
        p = lr_wmv(a1.z, b1.z, s1.z); om[6] = p.m; ov[6] = p.v;
        p = lr_wmv(a1.w, b1.w, s1.w); om[7] = p.m; ov[7] = p.v;
        wm8[i] = om;
        wv8[i] = ov;
    }
}

// ---------------------------------------------------------------------------
// Fused dual GEMM, 8-phase pipeline with FRAGMENT DOUBLE-BUFFERING:
//   BM=256 x BN=128, BK=64, 512 threads = 8 waves (4M x 2N), 64x64 dual acc.
//   LDS 128 KB (2 K-tile buffers x {X 32K | Wm 16K | Wv 16K}), XOR-swizzled.
//   ROUND-3 CHANGE: each phase is now
//     [16 MFMA on fragments read LAST phase] -> [ds_reads for NEXT phase]
//     -> [STG 2 gl_lds] -> [VM6 on even phases] -> s_barrier        (1 bar/phase)
//   The MFMA cluster has NO dependency on this phase's reads, so the LDS
//   port services the next phase's read burst underneath the current MFMA
//   cluster (reads are a full ~600cy phase old when consumed -> lgkm free).
//   Round-2 showed the reads' service time was naked on the critical path.
//   Publication/re-stage audit (new read positions, VM6 at even-phase ends):
//   every region is vmcnt-forced + barrier-published exactly >=1 barrier
//   before its read phase, and re-staged >=2 barriers after its last read's
//   forced completion. Buffers: A0/A1 alternate per kh-pair, Ba/Bb per phase
//   parity — all compile-time indexed (no scratch).
// ---------------------------------------------------------------------------
#define BM 256
#define BN 128
#define BK 64

__device__ inline void gl_lds16(const f16* g, f16* l) {
    __builtin_amdgcn_global_load_lds(
        (const __attribute__((address_space(1))) unsigned int*)g,
        (__attribute__((address_space(3))) unsigned int*)l,
        16, 0, 0);
}

#define VM8 asm volatile("s_waitcnt vmcnt(8)")
#define VM6 asm volatile("s_waitcnt vmcnt(6)")
#define VM4 asm volatile("s_waitcnt vmcnt(4)")
#define VM0 asm volatile("s_waitcnt vmcnt(0)")
#define VMNONE (void)0

__global__ __launch_bounds__(512, 2)
void fused_dual_gemm(const f16* __restrict__ Xb,
                     const f16* __restrict__ Wm, const f16* __restrict__ Wv,
                     const float* __restrict__ eps, float* __restrict__ out) {
    __shared__ f16 smem[65536];                // 128 KB
    // elem offsets: X(p,kh) = p*32768 + kh*8192            (256 rows x 32)
    //               Wm(p,kh) = 16384 + p*32768 + kh*8192   (128 rows x 32)
    //               Wv(p,kh) = Wm + 4096

    const int tid  = threadIdx.x;
    const int lane = tid & 63;
    const int wave = tid >> 6;

    const int bm = blockIdx.y * BM;
    const int bn = blockIdx.x * BN;

    // ---- staging source (per-lane pre-swizzled granule): chunk = 16 rows x 64B.
    const int srow = lane >> 2;
    const int scol = (((lane & 3) ^ ((lane >> 3) & 3)) << 3);   // elems
    const f16* gX = Xb + (size_t)(bm + 32 * wave + srow) * I_DIM + scol;
    const f16* gM = Wm + (size_t)(bn + 16 * wave + srow) * I_DIM + scol;
    const f16* gV = Wv + (size_t)(bn + 16 * wave + srow) * I_DIM + scol;
    f16* ldsX = smem + wave * 1024;            // + p*32768 + kh*8192 (+512 chunk 1)
    f16* ldsW = smem + 16384 + wave * 512;     // + p*32768 + kh*8192 (+4096 for Wv)

    // ---- fragment geometry (16x16x32: row = lane&15, granule = lane>>4)
    const int fr  = lane & 15;
    const int sg8 = (((lane >> 4) ^ ((fr >> 1) & 3)) << 3);     // swizzled granule
    const int m0 = (wave >> 1) << 6;           // 4 M-waves: 0,64,128,192
    const int n0 = (wave & 1) << 6;            // 2 N-waves: 0,64

    f32x4 accM[4][4];
    f32x4 accV[4][4];
    const f32x4 z = {0.0f, 0.0f, 0.0f, 0.0f};
#pragma unroll
    for (int mi = 0; mi < 4; ++mi)
#pragma unroll
        for (int ni = 0; ni < 4; ++ni) { accM[mi][ni] = z; accV[mi][ni] = z; }

    // fragment double-buffers (all statically indexed)
    f16x8 A0[4], A1[4], A2c[4], Ba[4], Bb[4];

#define STAGE_X(kelem, reg) do {                                               \
        gl_lds16(gX + (kelem),              ldsX + (reg));                     \
        gl_lds16(gX + (kelem) + 16 * I_DIM, ldsX + (reg) + 512);               \
    } while (0)
#define STAGE_W(kelem, reg) do {                                               \
        gl_lds16(gM + (kelem), ldsW + (reg));                                  \
        gl_lds16(gV + (kelem), ldsW + (reg) + 4096);                           \
    } while (0)

#define RD_A(DST, RX) do {                                                     \
        DST[0] = *(const f16x8*)(smem + (RX) + (m0 +  0 + fr) * 32 + sg8);     \
        DST[1] = *(const f16x8*)(smem + (RX) + (m0 + 16 + fr) * 32 + sg8);     \
        DST[2] = *(const f16x8*)(smem + (RX) + (m0 + 32 + fr) * 32 + sg8);     \
        DST[3] = *(const f16x8*)(smem + (RX) + (m0 + 48 + fr) * 32 + sg8);     \
    } while (0)
// H=0: rows n0+{0,16}+fr (ni 0,1); H=1: rows n0+{32,48}+fr (ni 2,3); m and v
#define RD_B(DST, RW, H) do {                                                  \
        DST[0] = *(const f16x8*)(smem + (RW)        + (n0 + (H)*32 +  0 + fr) * 32 + sg8); \
        DST[1] = *(const f16x8*)(smem + (RW) + 4096 + (n0 + (H)*32 +  0 + fr) * 32 + sg8); \
        DST[2] = *(const f16x8*)(smem + (RW)        + (n0 + (H)*32 + 16 + fr) * 32 + sg8); \
        DST[3] = *(const f16x8*)(smem + (RW) + 4096 + (n0 + (H)*32 + 16 + fr) * 32 + sg8); \
    } while (0)

#define MFMA16(AC, BB, NI0, NI1) do {                                          \
        __builtin_amdgcn_s_setprio(1);                                         \
        _Pragma("unroll")                                                      \
        for (int mi = 0; mi < 4; ++mi) {                                       \
            accM[mi][NI0] = __builtin_amdgcn_mfma_f32_16x16x32_f16(AC[mi],  BB[0], accM[mi][NI0], 0, 0, 0); \
            accV[mi][NI0] = __builtin_amdgcn_mfma_f32_16x16x32_f16(A2c[mi], BB[1], accV[mi][NI0], 0, 0, 0); \
            accM[mi][NI1] = __builtin_amdgcn_mfma_f32_16x16x32_f16(AC[mi],  BB[2], accM[mi][NI1], 0, 0, 0); \
            accV[mi][NI1] = __builtin_amdgcn_mfma_f32_16x16x32_f16(A2c[mi], BB[3], accV[mi][NI1], 0, 0, 0); \
        }                                                                      \
        __builtin_amdgcn_s_setprio(0);                                         \
    } while (0)

// even phase: a2; MFMA(ni 0,1) on AC,Ba; read Bb <- same region n23; STG; VM; bar
#define PH_EVEN(AC, RWcur, STG, VM) do {                                       \
        _Pragma("unroll")                                                      \
        for (int mi = 0; mi < 4; ++mi) A2c[mi] = AC[mi] * AC[mi];              \
        MFMA16(AC, Ba, 0, 1);                                                  \
        RD_B(Bb, RWcur, 1);                                                    \
        STG; VM; __builtin_amdgcn_s_barrier();                                 \
    } while (0)
// odd phase: MFMA(ni 2,3) on AC,Bb; read ANext <- RXn, Ba <- RWn n01; STG; bar
#define PH_ODD(AC, ANext, RXn, RWn, STG, VM) do {                              \
        MFMA16(AC, Bb, 2, 3);                                                  \
        RD_A(ANext, RXn);                                                      \
        RD_B(Ba, RWn, 0);                                                      \
        STG; VM; __builtin_amdgcn_s_barrier();                                 \
    } while (0)

    // ---- prologue: stage {X,W}(t0)k0, {X,W}(t0)k1, {X,W}(t1)k0 = 12 loads;
    // force the oldest 4 (tile0 kh0), then preload P0's fragments.
    STAGE_X(0, 0);      STAGE_W(0, 0);
    STAGE_X(32, 8192);  STAGE_W(32, 8192);
    STAGE_X(64, 32768); STAGE_W(64, 32768);
    VM8;
    __builtin_amdgcn_s_barrier();
    RD_A(A0, 0);
    RD_B(Ba, 16384, 0);

    // ---- main loop: 31 iterations x 2 K-tiles (tiles 0..61), prefetch 2 ahead.
    // Per phase, reads serve the NEXT phase; VM6 at even-phase ends publishes
    // each region exactly one barrier before its (shifted-early) read phase.
#pragma unroll 1
    for (int i = 0; i < 31; ++i) {
        const int kb = i * 128;
        PH_EVEN(A0, 16384,            STAGE_X(kb +  96, 40960), VM6);    // P0 t0k0 ni01
        PH_ODD (A0, A1, 8192, 24576,  STAGE_W(kb +  96, 40960), VMNONE); // P1 t0k0 ni23
        PH_EVEN(A1, 24576,            STAGE_X(kb + 128,     0), VM6);    // P2 t0k1 ni01
        PH_ODD (A1, A0, 32768, 49152, STAGE_W(kb + 128,     0), VMNONE); // P3 t0k1 ni23
        PH_EVEN(A0, 49152,            STAGE_X(kb + 160,  8192), VM6);    // P4 t1k0 ni01
        PH_ODD (A0, A1, 40960, 57344, STAGE_W(kb + 160,  8192), VMNONE); // P5 t1k0 ni23
        PH_EVEN(A1, 57344,            STAGE_X(kb + 192, 32768), VM6);    // P6 t1k1 ni01
        PH_ODD (A1, A0, 0, 16384,     STAGE_W(kb + 192, 32768), VMNONE); // P7 t1k1 ni23
    }

    // ---- tail: tiles 62,63. Only X/W(63,k1) still to issue; drain 6->4->0,
    // each VM placed one phase before the region's read (audited).
    PH_EVEN(A0, 16384,            STAGE_X(4064, 40960), VM6);    // TP0
    PH_ODD (A0, A1, 8192, 24576,  STAGE_W(4064, 40960), VMNONE); // TP1
    PH_EVEN(A1, 24576,            VMNONE, VM4);                  // TP2
    PH_ODD (A1, A0, 32768, 49152, VMNONE, VMNONE);               // TP3
    PH_EVEN(A0, 49152,            VMNONE, VM0);                  // TP4
    PH_ODD (A0, A1, 40960, 57344, VMNONE, VMNONE);               // TP5
    PH_EVEN(A1, 57344,            VMNONE, VMNONE);               // TP6
    MFMA16(A1, Bb, 2, 3);                                        // TP7 (no reads)

    // ---- epilogue (register-resident): C/D layout col = lane&15, row = (lane>>4)*4 + r
    const int oc  = lane & 15;
    const int orb = (lane >> 4) << 2;
#pragma unroll
    for (int mi = 0; mi < 4; ++mi) {
#pragma unroll
        for (int ni = 0; ni < 4; ++ni) {
            const int gn = bn + n0 + ni * 16 + oc;
            const int gm = bm + m0 + mi * 16 + orb;
#pragma unroll
            for (int r = 0; r < 4; ++r) {
                const size_t off = (size_t)(gm + r) * O_DIM + gn;
                const float mu = accM[mi][ni][r];
                const float vv = accV[mi][ni][r];
                out[off] = fmaf(sqrtf(fmaxf(vv, 1e-8f)), eps[off], mu);
            }
        }
    }
#undef PH_ODD
#undef PH_EVEN
#undef MFMA16
#undef RD_B
#undef RD_A
#undef STAGE_W
#undef STAGE_X
}

// ---------------------------------------------------------------------------
extern "C" void kernel_launch(void* const* d_in, const int* in_sizes, int n_in,
                              void* d_out, int out_size, void* d_ws, size_t ws_size,
                              hipStream_t stream) {
    const float* x   = (const float*)d_in[0];
    const float* tn  = (const float*)d_in[1];
    const float* tp  = (const float*)d_in[2];
    const float* sc  = (const float*)d_in[3];
    const float* eps = (const float*)d_in[4];
    float* out = (float*)d_out;

    const size_t NE = (size_t)O_DIM * I_DIM;   // 16.7M
    f16* xb = (f16*)d_ws;                      // 32 MB
    f16* wm = xb + NE;                         // 32 MB
    f16* wv = wm + NE;                         // 32 MB

    const int nbx = (int)(NE / 8 / 256);       // 8192 (x path)
    const int nbw = (int)(NE / 8 / 256);       // 8192 (weight path)
    prep_all<<<nbx + nbw, 256, 0, stream>>>(
        (const float4*)x, (f16x8*)xb,
        (const float4*)tn, (const float4*)tp, (const float4*)sc,
        (f16x8*)wm, (f16x8*)wv, nbx);

    dim3 grid(O_DIM / BN, B_DIM / BM);   // (32, 16)
    fused_dual_gemm<<<grid, 512, 0, stream>>>(
        (const f16*)xb, (const f16*)wm, (const f16*)wv, eps, out);
}